// Round 1
// baseline (100.943 us; speedup 1.0000x reference)
//
#include <hip/hip_runtime.h>
#include <hip/hip_bf16.h>
#include <stdint.h>

typedef __attribute__((ext_vector_type(8))) short short8;
typedef __attribute__((ext_vector_type(4))) float f32x4;

static __device__ __forceinline__ short to_bf16s(float f) {
  __hip_bfloat16 h = __float2bfloat16(f);
  return __builtin_bit_cast(short, h);
}

// ---------------------------------------------------------------------------
// Detect whether edge_index arrived as int64 (odd dwords all zero) or int32.
// Writes 1 to *flag if int64-layout, else 0.
__global__ void k_detect(const int* __restrict__ s32, unsigned* __restrict__ flag) {
  __shared__ unsigned z;
  if (threadIdx.x == 0) z = 0u;
  __syncthreads();
  unsigned cnt = 0;
  for (int i = threadIdx.x; i < 1024; i += 256)
    if (s32[2 * i + 1] == 0) cnt++;
  atomicAdd(&z, cnt);
  __syncthreads();
  if (threadIdx.x == 0) *flag = (z > 512u) ? 1u : 0u;
}

// Histogram of src = edge_index[0] into deg[N] (dst is algebraically unused).
__global__ void k_hist(const int* __restrict__ s32, unsigned* __restrict__ deg,
                       const unsigned* __restrict__ flag, int E) {
  int i = blockIdx.x * blockDim.x + threadIdx.x;
  if (i >= E) return;
  int v = (*flag) ? s32[2 * i] : s32[i];  // int64: value in even dword (LE)
  atomicAdd(&deg[v], 1u);
}

// ---------------------------------------------------------------------------
// W1 (f32 [128][128], h = x@W1) -> bf16 B-fragments for mfma_f32_16x16x32_bf16.
// slot = (ct*4+ks)*64 + lane holds 8 bf16: col = ct*16+(lane&15),
// k = ks*32 + (lane>>4)*8 + e.
__global__ void k_prep(const float* __restrict__ W1, short* __restrict__ frag) {
  int idx = blockIdx.x * blockDim.x + threadIdx.x;  // 0..16383 = k*128 + col
  int k = idx >> 7, col = idx & 127;
  int ct = col >> 4, ks = k >> 5, lh = (k >> 3) & 3, e = k & 7;
  int lane = lh * 16 + (col & 15);
  frag[((ct * 4 + ks) * 64 + lane) * 8 + e] = to_bf16s(W1[idx]);
}

// ---------------------------------------------------------------------------
// Main: s[j] = sum_n (1+deg[n]) * relu( (X@W1)[n][j] + b1[j] ),  j = 0..127.
// Each wave processes 16-node chunks: A-frags from global (bf16-converted),
// B-frags (W1) from LDS, 8x4 = 32 MFMAs/chunk, row-reduce in epilogue.
__global__ __launch_bounds__(256) void k_main(
    const float* __restrict__ X, const short* __restrict__ w1frag,
    const float* __restrict__ b1, const unsigned* __restrict__ deg,
    float* __restrict__ s_out, int nNodes) {
  __shared__ short w1s[16384];   // 32 KiB: [(ct*4+ks)*64 + lane][8]
  __shared__ float sred[128];

  int tid = threadIdx.x;
  {  // coalesced copy of pre-converted fragments into LDS
    const f32x4* src = reinterpret_cast<const f32x4*>(w1frag);
    f32x4* dst = reinterpret_cast<f32x4*>(w1s);
#pragma unroll
    for (int i = 0; i < 8; ++i) dst[tid + i * 256] = src[tid + i * 256];
  }
  if (tid < 128) sred[tid] = 0.f;
  __syncthreads();

  int lane = tid & 63, wave = tid >> 6;
  int rA = lane & 15;          // A-row within chunk / C-col low bits
  int kA = (lane >> 4) * 8;    // A k-offset within 32-wide k-group

  float b1r[8];
#pragma unroll
  for (int ct = 0; ct < 8; ++ct) b1r[ct] = b1[ct * 16 + rA];

  float sl[8] = {0, 0, 0, 0, 0, 0, 0, 0};

  int gw = blockIdx.x * 4 + wave;
  int nw = gridDim.x * 4;
  int nChunks = (nNodes + 15) >> 4;

  for (int c = gw; c < nChunks; c += nw) {
    int row0 = c << 4;
    int rowA = row0 + rA;
    if (rowA > nNodes - 1) rowA = nNodes - 1;  // tail clamp (N%16==0 normally)
    const float* xp = X + (size_t)rowA * 128 + kA;

    f32x4 xv[8];
#pragma unroll
    for (int ks = 0; ks < 4; ++ks) {
      xv[2 * ks]     = *reinterpret_cast<const f32x4*>(xp + ks * 32);
      xv[2 * ks + 1] = *reinterpret_cast<const f32x4*>(xp + ks * 32 + 4);
    }

    f32x4 acc[8];
#pragma unroll
    for (int ct = 0; ct < 8; ++ct) acc[ct] = f32x4{0.f, 0.f, 0.f, 0.f};

#pragma unroll
    for (int ks = 0; ks < 4; ++ks) {
      short8 a;
#pragma unroll
      for (int e = 0; e < 4; ++e) a[e] = to_bf16s(xv[2 * ks][e]);
#pragma unroll
      for (int e = 0; e < 4; ++e) a[4 + e] = to_bf16s(xv[2 * ks + 1][e]);
#pragma unroll
      for (int ct = 0; ct < 8; ++ct) {
        short8 b = *reinterpret_cast<const short8*>(&w1s[((ct * 4 + ks) * 64 + lane) * 8]);
        acc[ct] = __builtin_amdgcn_mfma_f32_16x16x32_bf16(a, b, acc[ct], 0, 0, 0);
      }
    }

    // epilogue: C elem (ct, r): row = row0 + (lane>>4)*4 + r, col = ct*16+(lane&15)
#pragma unroll
    for (int r = 0; r < 4; ++r) {
      int row = row0 + (lane >> 4) * 4 + r;
      float w = (row < nNodes) ? (1.0f + (float)deg[row]) : 0.0f;
#pragma unroll
      for (int ct = 0; ct < 8; ++ct) {
        float t = acc[ct][r] + b1r[ct];
        sl[ct] += w * fmaxf(t, 0.f);
      }
    }
  }

  // fold the 4 lane-groups (lane>>4) onto lanes 0..15, then into LDS
#pragma unroll
  for (int ct = 0; ct < 8; ++ct) {
    float v = sl[ct];
    v += __shfl_xor(v, 16);
    v += __shfl_xor(v, 32);
    if ((lane >> 4) == 0) atomicAdd(&sred[ct * 16 + rA], v);
  }
  __syncthreads();
  if (tid < 128) atomicAdd(&s_out[tid], sred[tid]);
}

// ---------------------------------------------------------------------------
// out = ((s@W2 + (N+E)*b2)/N) @ Wp + bp
__global__ void k_final(const float* __restrict__ s, const float* __restrict__ W2,
                        const float* __restrict__ b2, const float* __restrict__ Wp,
                        const float* __restrict__ bp, float* __restrict__ out,
                        float totalW, float invN) {
  __shared__ float pooled[128];
  int t = threadIdx.x;  // 128 threads
  float acc = totalW * b2[t];
  for (int k = 0; k < 128; ++k) acc += s[k] * W2[k * 128 + t];
  pooled[t] = acc * invN;
  __syncthreads();
  if (t < 64) {
    float o = 0.f;
    for (int j = 0; j < 128; ++j) o += pooled[j] * Wp[j * 64 + t];
    out[t] = o + bp[t];
  }
}

// ---------------------------------------------------------------------------
extern "C" void kernel_launch(void* const* d_in, const int* in_sizes, int n_in,
                              void* d_out, int out_size, void* d_ws, size_t ws_size,
                              hipStream_t stream) {
  const float* X  = (const float*)d_in[0];
  const int*   ei = (const int*)d_in[1];
  const float* W1 = (const float*)d_in[2];
  const float* b1 = (const float*)d_in[3];
  const float* W2 = (const float*)d_in[4];
  const float* b2 = (const float*)d_in[5];
  const float* Wp = (const float*)d_in[6];
  const float* bp = (const float*)d_in[7];

  int N = in_sizes[0] / 128;
  int E = in_sizes[1] / 2;

  // workspace layout
  size_t off_s    = (((size_t)N * 4) + 15) & ~(size_t)15;  // deg[N] u32 first
  size_t off_frag = off_s + 512;                           // s[128] f32
  size_t off_flag = off_frag + 16384 * sizeof(short);      // w1 frags (32 KiB)

  unsigned* deg   = (unsigned*)d_ws;
  float*    s     = (float*)((char*)d_ws + off_s);
  short*    frag  = (short*)((char*)d_ws + off_frag);
  unsigned* flag  = (unsigned*)((char*)d_ws + off_flag);

  // zero deg + s accumulators (every call: harness does not re-poison)
  hipMemsetAsync(d_ws, 0, off_s + 512, stream);

  k_detect<<<1, 256, 0, stream>>>(ei, flag);
  k_hist<<<(E + 255) / 256, 256, 0, stream>>>(ei, deg, flag, E);
  k_prep<<<64, 256, 0, stream>>>(W1, frag);
  k_main<<<1024, 256, 0, stream>>>(X, frag, b1, deg, s, N);
  k_final<<<1, 128, 0, stream>>>(s, W2, b2, Wp, bp, (float*)d_out,
                                 (float)N + (float)E, 1.0f / (float)N);
}

// Round 2
// 79.126 us; speedup vs baseline: 1.2757x; 1.2757x over previous
//
#include <hip/hip_runtime.h>
#include <hip/hip_bf16.h>
#include <stdint.h>

typedef __attribute__((ext_vector_type(8))) short short8;
typedef __attribute__((ext_vector_type(4))) float f32x4;

static __device__ __forceinline__ short to_bf16s(float f) {
  __hip_bfloat16 h = __float2bfloat16(f);
  return __builtin_bit_cast(short, h);
}

static __device__ __forceinline__ int xcd_id() {
  unsigned x;
  asm volatile("s_getreg_b32 %0, hwreg(HW_REG_XCC_ID)" : "=s"(x));
  return (int)(x & 7);
}

// ---------------------------------------------------------------------------
// Histogram of src = edge_index[0] (dst is algebraically unused: the final
// mean over all nodes makes segment_sum collapse to sum_e h[src[e]]).
// Per-XCD private copies + workgroup-scope atomics -> atomics execute in the
// XCD-local L2 instead of 32B device-scope fabric RMWs.
__global__ __launch_bounds__(256) void k_hist(const int* __restrict__ s32,
                                              unsigned* __restrict__ deg,
                                              int E, int N, int nc) {
  __shared__ int is64s;
  int tid = threadIdx.x;
  if (tid < 64) {  // layout detect: int64 -> odd dwords (high words) are 0
    unsigned long long b = __ballot(s32[2 * tid + 1] == 0);
    if (tid == 0) is64s = (__popcll(b) > 32) ? 1 : 0;
  }
  __syncthreads();
  int is64 = is64s;
  unsigned* my = deg + (nc > 1 ? (size_t)xcd_id() * N : 0);
  int stride = gridDim.x * blockDim.x;
  for (int i = blockIdx.x * blockDim.x + tid; i < E; i += stride) {
    int v = is64 ? s32[2 * i] : s32[i];
    if (nc > 1)
      __hip_atomic_fetch_add(&my[v], 1u, __ATOMIC_RELAXED,
                             __HIP_MEMORY_SCOPE_WORKGROUP);
    else
      atomicAdd(&my[v], 1u);
  }
}

// ---------------------------------------------------------------------------
// Blocks [0,64): W1 (f32 [128][128], h=x@W1) -> bf16 B-fragments for
//   mfma_f32_16x16x32_bf16. slot=(ct*4+ks)*64+lane holds 8 bf16:
//   col = ct*16+(lane&15), k = ks*32+(lane>>4)*8+e.
// Blocks [64,...): reduce the nc degree copies into float weight 1+deg.
__global__ __launch_bounds__(256) void k_mid(const float* __restrict__ W1,
                                             short* __restrict__ frag,
                                             const unsigned* __restrict__ deg,
                                             float* __restrict__ wdeg,
                                             int N, int nc) {
  int b = blockIdx.x;
  if (b < 64) {
    int idx = b * 256 + threadIdx.x;  // k*128 + col
    int k = idx >> 7, col = idx & 127;
    int ct = col >> 4, ks = k >> 5, lh = (k >> 3) & 3, e = k & 7;
    int lane = lh * 16 + (col & 15);
    frag[((ct * 4 + ks) * 64 + lane) * 8 + e] = to_bf16s(W1[idx]);
  } else {
    int n = (b - 64) * 256 + threadIdx.x;
    if (n < N) {
      unsigned t = 0;
      for (int c = 0; c < nc; ++c) t += deg[(size_t)c * N + n];
      wdeg[n] = 1.0f + (float)t;
    }
  }
}

// ---------------------------------------------------------------------------
// Main: s[j] = sum_n wdeg[n] * relu( (X@W1)[n][j] + b1[j] ),  j = 0..127.
// Each wave processes 16-node chunks: A-frags from global (bf16-converted),
// B-frags (W1) from LDS, 8x4 = 32 MFMAs/chunk, row-reduce in epilogue.
__global__ __launch_bounds__(256) void k_main(
    const float* __restrict__ X, const short* __restrict__ w1frag,
    const float* __restrict__ b1, const float* __restrict__ wdeg,
    float* __restrict__ s_out, int nNodes, int nc) {
  __shared__ short w1s[16384];  // 32 KiB: [(ct*4+ks)*64 + lane][8]
  __shared__ float sred[128];

  int tid = threadIdx.x;
  {  // coalesced copy of pre-converted fragments into LDS
    const f32x4* src = reinterpret_cast<const f32x4*>(w1frag);
    f32x4* dst = reinterpret_cast<f32x4*>(w1s);
#pragma unroll
    for (int i = 0; i < 8; ++i) dst[tid + i * 256] = src[tid + i * 256];
  }
  if (tid < 128) sred[tid] = 0.f;
  __syncthreads();

  int lane = tid & 63, wave = tid >> 6;
  int rA = lane & 15;        // A-row within chunk / C-col low bits
  int kA = (lane >> 4) * 8;  // A k-offset within 32-wide k-group

  float b1r[8];
#pragma unroll
  for (int ct = 0; ct < 8; ++ct) b1r[ct] = b1[ct * 16 + rA];

  float sl[8] = {0, 0, 0, 0, 0, 0, 0, 0};

  int gw = blockIdx.x * 4 + wave;
  int nw = gridDim.x * 4;
  int nChunks = (nNodes + 15) >> 4;

  for (int c = gw; c < nChunks; c += nw) {
    int row0 = c << 4;
    int rowA = row0 + rA;
    if (rowA > nNodes - 1) rowA = nNodes - 1;  // tail clamp (N%16==0 normally)
    const float* xp = X + (size_t)rowA * 128 + kA;

    f32x4 xv[8];
#pragma unroll
    for (int ks = 0; ks < 4; ++ks) {
      xv[2 * ks]     = *reinterpret_cast<const f32x4*>(xp + ks * 32);
      xv[2 * ks + 1] = *reinterpret_cast<const f32x4*>(xp + ks * 32 + 4);
    }

    f32x4 acc[8];
#pragma unroll
    for (int ct = 0; ct < 8; ++ct) acc[ct] = f32x4{0.f, 0.f, 0.f, 0.f};

#pragma unroll
    for (int ks = 0; ks < 4; ++ks) {
      short8 a;
#pragma unroll
      for (int e = 0; e < 4; ++e) a[e] = to_bf16s(xv[2 * ks][e]);
#pragma unroll
      for (int e = 0; e < 4; ++e) a[4 + e] = to_bf16s(xv[2 * ks + 1][e]);
#pragma unroll
      for (int ct = 0; ct < 8; ++ct) {
        short8 bfr = *reinterpret_cast<const short8*>(
            &w1s[((ct * 4 + ks) * 64 + lane) * 8]);
        acc[ct] = __builtin_amdgcn_mfma_f32_16x16x32_bf16(a, bfr, acc[ct], 0, 0, 0);
      }
    }

    // epilogue: C elem (ct, r): row = row0+(lane>>4)*4+r, col = ct*16+(lane&15)
#pragma unroll
    for (int r = 0; r < 4; ++r) {
      int row = row0 + (lane >> 4) * 4 + r;
      float w = (row < nNodes) ? wdeg[row] : 0.0f;
#pragma unroll
      for (int ct = 0; ct < 8; ++ct) {
        float t = acc[ct][r] + b1r[ct];
        sl[ct] += w * fmaxf(t, 0.f);
      }
    }
  }

  // fold the 4 lane-groups onto lanes 0..15, then into LDS, then one
  // XCD-local (workgroup-scope, L2-resident) flush per column.
#pragma unroll
  for (int ct = 0; ct < 8; ++ct) {
    float v = sl[ct];
    v += __shfl_xor(v, 16);
    v += __shfl_xor(v, 32);
    if ((lane >> 4) == 0) atomicAdd(&sred[ct * 16 + rA], v);
  }
  __syncthreads();
  if (tid < 128) {
    float* sc = s_out + (nc > 1 ? xcd_id() * 128 : 0);
    if (nc > 1)
      __hip_atomic_fetch_add(&sc[tid], sred[tid], __ATOMIC_RELAXED,
                             __HIP_MEMORY_SCOPE_WORKGROUP);
    else
      atomicAdd(&sc[tid], sred[tid]);
  }
}

// ---------------------------------------------------------------------------
// out = (( (sum_c s_c)@W2 + (N+E)*b2 )/N) @ Wp + bp
__global__ void k_final(const float* __restrict__ s, const float* __restrict__ W2,
                        const float* __restrict__ b2, const float* __restrict__ Wp,
                        const float* __restrict__ bp, float* __restrict__ out,
                        float totalW, float invN, int nc) {
  __shared__ float pooled[128];
  __shared__ float sv[128];
  int t = threadIdx.x;  // 128 threads
  float ssum = 0.f;
  for (int c = 0; c < nc; ++c) ssum += s[c * 128 + t];
  sv[t] = ssum;
  __syncthreads();
  float acc = totalW * b2[t];
  for (int k = 0; k < 128; ++k) acc += sv[k] * W2[k * 128 + t];
  pooled[t] = acc * invN;
  __syncthreads();
  if (t < 64) {
    float o = 0.f;
    for (int j = 0; j < 128; ++j) o += pooled[j] * Wp[j * 64 + t];
    out[t] = o + bp[t];
  }
}

// ---------------------------------------------------------------------------
extern "C" void kernel_launch(void* const* d_in, const int* in_sizes, int n_in,
                              void* d_out, int out_size, void* d_ws, size_t ws_size,
                              hipStream_t stream) {
  const float* X  = (const float*)d_in[0];
  const int*   ei = (const int*)d_in[1];
  const float* W1 = (const float*)d_in[2];
  const float* b1 = (const float*)d_in[3];
  const float* W2 = (const float*)d_in[4];
  const float* b2 = (const float*)d_in[5];
  const float* Wp = (const float*)d_in[6];
  const float* bp = (const float*)d_in[7];

  int N = in_sizes[0] / 128;
  int E = in_sizes[1] / 2;

  // ws layout: deg copies [nc*N u32] | s copies [nc*128 f32] | wdeg [N f32]
  //            | frag [16384 short]
  size_t need8 = (size_t)8 * N * 4 + 8 * 512 + (size_t)N * 4 + 32768 + 64;
  int nc = (ws_size >= need8) ? 8 : 1;

  size_t off = 0;
  unsigned* deg = (unsigned*)d_ws;
  off += (size_t)nc * N * 4;
  float* sc = (float*)((char*)d_ws + off);
  off += (size_t)nc * 512;
  float* wdeg = (float*)((char*)d_ws + off);
  off += (size_t)N * 4;
  off = (off + 15) & ~(size_t)15;
  short* frag = (short*)((char*)d_ws + off);

  // zero the atomic accumulators (harness does not re-poison between replays)
  hipMemsetAsync(d_ws, 0, (size_t)nc * N * 4 + (size_t)nc * 512, stream);

  k_hist<<<2048, 256, 0, stream>>>(ei, deg, E, N, nc);
  int midBlocks = 64 + (N + 255) / 256;
  k_mid<<<midBlocks, 256, 0, stream>>>(W1, frag, deg, wdeg, N, nc);
  k_main<<<1024, 256, 0, stream>>>(X, frag, b1, wdeg, sc, N, nc);
  k_final<<<1, 128, 0, stream>>>(sc, W2, b2, Wp, bp, (float*)d_out,
                                 (float)N + (float)E, 1.0f / (float)N, nc);
}